// Round 7
// baseline (79.267 us; speedup 1.0000x reference)
//
#include <hip/hip_runtime.h>
#include <stdint.h>

typedef _Float16 half8 __attribute__((ext_vector_type(8)));
typedef float f32x16 __attribute__((ext_vector_type(16)));

#define NPTS   4096
#define BATCH  16
#define BLOCK  256
#define HOTH   2048               // others per LDS stage (32 KB)
#define NCH    2                  // 2 stages cover all 4096 others
#define NBLK   1024               // tile(32 of 128 selves) x b(16) x dir(2) = 4/CU

// dist(s,o) = |s|^2 + (s.g + q), g = -2o, q = |o|^2, f16 hi/lo split.
// Record R = [ghx,ghy,ghz,glx,gly,glz,qh,ql]; both K-groups read the SAME
// record, the A-fragment differs per group (exact math, absmax 0):
//   grp0 (k=0..7):  A=[shx,shy,shz,0,0,0,1,0]        -> sh.gh + qh
//   grp1 (k=8..15): A=[slx,sly,slz,shx,shy,shz,0,1]  -> sl.gh + sh.gl + ql
// One 32x32x16 MFMA yields the full (to ~2^-24) distance tile.
// |s|^2 is added per self in the epilogue (constant shift commutes w/ min).
//
// REGISTER DISCIPLINE (the R4-R6 lesson): __launch_bounds__(256,4) caps the
// unified file at 128 regs/lane. unroll>1 clones the o-pair live range
// (2 rounds in flight = 96 acc regs) -> spill -> scratch latency in the hot
// loop (R4: 95 MB WRITE_SIZE). So: unroll 1, ONE o-pair (acc = m+zc+o0+o1
// = 64 exactly), and ILP restored via explicit next-round B prefetch regs.
__global__ __launch_bounds__(BLOCK, 4) void chamfer_all(
    const float* __restrict__ p1, const float* __restrict__ p2,
    float* __restrict__ out)
{
    __shared__ half8 REC[HOTH];   // 32 KB -> 4 blocks/CU, 4 waves/SIMD
    __shared__ float ws4[4];

    const int tid  = threadIdx.x;
    const int lane = tid & 63;
    const int n    = lane & 31;   // A row (self) / B col (other)
    const int grp  = lane >> 5;   // K-group
    const int wv   = tid >> 6;    // 0..3
    const int blk  = blockIdx.x;
    const int tile = blk & 31;    // fastest: 32 blocks share one other-set (L2)
    const int b    = (blk >> 5) & 15;
    const int dir  = blk >> 9;

    const float* selfp  = (dir ? p2 : p1) + (size_t)b * NPTS * 3;
    const float* otherp = (dir ? p1 : p2) + (size_t)b * NPTS * 3;

    // ---- A fragment: 32 selves per wave ----
    half8 a; float ssq;
    {
        const int s = tile * 128 + wv * 32 + n;
        const float x = selfp[s * 3], y = selfp[s * 3 + 1], z = selfp[s * 3 + 2];
        ssq = fmaf(x, x, fmaf(y, y, z * z));
        _Float16 hx = (_Float16)x, hy = (_Float16)y, hz = (_Float16)z;
        _Float16 lx = (_Float16)(x - (float)hx);
        _Float16 ly = (_Float16)(y - (float)hy);
        _Float16 lz = (_Float16)(z - (float)hz);
        const _Float16 c0 = (_Float16)0.f, c1 = (_Float16)1.f;
        if (grp == 0) { a[0]=hx; a[1]=hy; a[2]=hz; a[3]=c0; a[4]=c0; a[5]=c0; a[6]=c1; a[7]=c0; }
        else          { a[0]=lx; a[1]=ly; a[2]=lz; a[3]=hx; a[4]=hy; a[5]=hz; a[6]=c0; a[7]=c1; }
    }

    f32x16 m, zc;
#pragma unroll
    for (int r = 0; r < 16; ++r) { m[r] = 3.4e38f; zc[r] = 0.f; }

#pragma unroll 1
    for (int c = 0; c < NCH; ++c) {
        __syncthreads();   // REC safe to overwrite (all reads of prev chunk done)
        {   // Stage 8 others/thread. REC[k*256+tid]: 16 B lane stride -> no
            // bank conflicts. The k-permutation is min-invariant.
            const float4* src = (const float4*)(otherp + (size_t)c * HOTH * 3);
            float4 v0 = src[tid*6+0], v1 = src[tid*6+1], v2 = src[tid*6+2];
            float4 v3 = src[tid*6+3], v4 = src[tid*6+4], v5 = src[tid*6+5];
            float ox[8] = {v0.x, v0.w, v1.z, v2.y, v3.x, v3.w, v4.z, v5.y};
            float oy[8] = {v0.y, v1.x, v1.w, v2.z, v3.y, v4.x, v4.w, v5.z};
            float oz[8] = {v0.z, v1.y, v2.x, v2.w, v3.z, v4.y, v5.x, v5.w};
#pragma unroll
            for (int k = 0; k < 8; ++k) {
                float gx = -2.f * ox[k], gy = -2.f * oy[k], gz = -2.f * oz[k];
                float q  = fmaf(ox[k], ox[k], fmaf(oy[k], oy[k], oz[k] * oz[k]));
                _Float16 ghx = (_Float16)gx, ghy = (_Float16)gy, ghz = (_Float16)gz;
                half8 r;
                r[0] = ghx; r[1] = ghy; r[2] = ghz;
                r[3] = (_Float16)(gx - (float)ghx);
                r[4] = (_Float16)(gy - (float)ghy);
                r[5] = (_Float16)(gz - (float)ghz);
                _Float16 qh = (_Float16)q;
                r[6] = qh;
                r[7] = (_Float16)(q - (float)qh);
                REC[k * 256 + tid] = r;
            }
        }
        __syncthreads();

        // 32 rounds; unroll 1 + register prefetch of next round's B-pair.
        const half8* rp = REC + n;
        half8 c0 = rp[0];
        half8 c1 = rp[32];
#pragma unroll 1
        for (int g = 0; g < 32; ++g) {
            const int gn = ((g + 1) & 31) * 64;      // wrap: last prefetch benign
            half8 n0 = rp[gn];
            half8 n1 = rp[gn + 32];
            f32x16 o0 = __builtin_amdgcn_mfma_f32_32x32x16_f16(a, c0, zc, 0, 0, 0);
            f32x16 o1 = __builtin_amdgcn_mfma_f32_32x32x16_f16(a, c1, zc, 0, 0, 0);
#pragma unroll
            for (int r = 0; r < 16; ++r)
                m[r] = fminf(fminf(o0[r], o1[r]), m[r]);   // v_min3_f32
            c0 = n0; c1 = n1;
        }
    }

    // ---- epilogue: min over 32 cols, sum rows, add |s|^2, one atomic ----
#pragma unroll
    for (int mask = 1; mask <= 16; mask <<= 1)
#pragma unroll
        for (int r = 0; r < 16; ++r)
            m[r] = fminf(m[r], __shfl_xor((float)m[r], mask));

    float rowsum = 0.f;
#pragma unroll
    for (int r = 0; r < 16; ++r) rowsum += m[r];
    rowsum += __shfl_xor(rowsum, 32);       // other K-group's 16 rows

    float sv = grp ? 0.f : ssq;             // each self counted once
#pragma unroll
    for (int mask = 1; mask <= 16; mask <<= 1) sv += __shfl_xor(sv, mask);

    if (lane == 0) ws4[wv] = rowsum + sv;
    __syncthreads();
    if (tid == 0)
        atomicAdd(out, (ws4[0] + ws4[1] + ws4[2] + ws4[3]) * (1.0f / BATCH));
}

extern "C" void kernel_launch(void* const* d_in, const int* in_sizes, int n_in,
                              void* d_out, int out_size, void* d_ws, size_t ws_size,
                              hipStream_t stream) {
    const float* p1 = (const float*)d_in[0];
    const float* p2 = (const float*)d_in[1];
    // No workspace usage: out[0] is zeroed by the harness each iteration and
    // accumulated via device-scope float atomics (error << 5.88 threshold).
    chamfer_all<<<dim3(NBLK), dim3(BLOCK), 0, stream>>>(p1, p2, (float*)d_out);
}